// Round 1
// baseline (1978.103 us; speedup 1.0000x reference)
//
#include <hip/hip_runtime.h>
#include <stdint.h>

#define BATCH   8192
#define NTOT    4096
#define HID     256
#define NLAYERS 8
#define NMASK   2048
#define LDK     40   // LDS K-stride (32 + 8 pad), keeps 16B alignment

typedef float  f32x4  __attribute__((ext_vector_type(4)));
typedef __bf16 bf16x8 __attribute__((ext_vector_type(8)));
typedef unsigned short u16x8 __attribute__((ext_vector_type(8)));

__device__ __forceinline__ unsigned short f2bf(float f) {
    union { float f; unsigned u; } v; v.f = f;
    unsigned r = v.u + 0x7FFFu + ((v.u >> 16) & 1u);
    return (unsigned short)(r >> 16);
}
__device__ __forceinline__ float bf2f(unsigned short h) {
    union { float f; unsigned u; } v; v.u = ((unsigned)h) << 16;
    return v.f;
}
__device__ __forceinline__ void split2(float f, unsigned short& hi, unsigned short& lo) {
    hi = f2bf(f);
    lo = f2bf(f - bf2f(hi));
}

// ---------------------------------------------------------------------------
// Transpose + bf16 hi/lo split of weights: in [NL][K][N] fp32 -> out [NL][N][K]
// ---------------------------------------------------------------------------
__global__ __launch_bounds__(256) void split_transpose_kernel(
    const float* __restrict__ W,
    unsigned short* __restrict__ Whi,
    unsigned short* __restrict__ Wlo,
    int K, int N)
{
    __shared__ float tile[32][33];
    const int l  = blockIdx.z;
    const int k0 = blockIdx.x * 32;
    const int n0 = blockIdx.y * 32;
    const float* Wl = W + (size_t)l * K * N;
    const int tx = threadIdx.x & 31;
    const int ty = threadIdx.x >> 5;   // 0..7
#pragma unroll
    for (int it = 0; it < 4; ++it) {
        int r = ty + it * 8;
        tile[r][tx] = Wl[(size_t)(k0 + r) * N + (n0 + tx)];
    }
    __syncthreads();
    const size_t obase = (size_t)l * N * K;
#pragma unroll
    for (int it = 0; it < 4; ++it) {
        int r = ty + it * 8;                       // n offset within tile
        float v = tile[tx][r];                     // = Wl[k0+tx][n0+r]
        unsigned short hi, lo; split2(v, hi, lo);
        size_t oi = obase + (size_t)(n0 + r) * K + (k0 + tx);
        Whi[oi] = hi; Wlo[oi] = lo;
    }
}

// ---------------------------------------------------------------------------
// GEMM1/GEMM2: O = leaky_relu(A @ W + b), output stored as bf16 hi/lo split.
// GATHER=true: A = checkerboard-masked half of X (fp32, gathered+split on the fly)
// GATHER=false: A = pre-split bf16 hi/lo (row stride K)
// W pre-split, TRANSPOSED: Whi/Wlo are [HID][K] (n-major).
// Tile: 64x64, 4 waves, wave w handles m-rows [16w,16w+16), all 64 cols.
// ---------------------------------------------------------------------------
template<bool GATHER>
__global__ __launch_bounds__(256) void gemm_h(
    const float* __restrict__ X,
    const unsigned short* __restrict__ Ahi, const unsigned short* __restrict__ Alo,
    const unsigned short* __restrict__ Bhi, const unsigned short* __restrict__ Blo,
    const float* __restrict__ bias,
    unsigned short* __restrict__ Ohi, unsigned short* __restrict__ Olo,
    int K, int parity)
{
    __shared__ unsigned short As_h[64 * LDK], As_l[64 * LDK];
    __shared__ unsigned short Bs_h[64 * LDK], Bs_l[64 * LDK];

    const int t = threadIdx.x;
    const int row0 = blockIdx.x * 64;
    const int col0 = blockIdx.y * 64;
    const int w  = t >> 6;
    const int L  = t & 63;
    const int q  = L >> 4;     // 0..3
    const int nl = L & 15;     // 0..15
    const int sm = t >> 2;     // staging row 0..63
    const int sc = (t & 3) * 8;// staging k offset {0,8,16,24}

    f32x4 acc[4] = {{0,0,0,0},{0,0,0,0},{0,0,0,0},{0,0,0,0}};

    const int nk = K / 32;
    for (int kt = 0; kt < nk; ++kt) {
        // ---- stage A ----
        if (GATHER) {
            // spatial row r == kt, masked component e constant across tile
            const int e = (kt + parity) & 1;
            const float4* src = reinterpret_cast<const float4*>(
                X + (size_t)(row0 + sm) * NTOT + (size_t)kt * 64 + 2 * sc);
            u16x8 vh, vl;
#pragma unroll
            for (int i = 0; i < 4; ++i) {
                float4 f = src[i];
                float v0 = e ? f.y : f.x;
                float v1 = e ? f.w : f.z;
                unsigned short h0, l0, h1, l1;
                split2(v0, h0, l0); split2(v1, h1, l1);
                vh[2*i] = h0; vh[2*i+1] = h1;
                vl[2*i] = l0; vl[2*i+1] = l1;
            }
            *(u16x8*)&As_h[sm * LDK + sc] = vh;
            *(u16x8*)&As_l[sm * LDK + sc] = vl;
        } else {
            *(u16x8*)&As_h[sm * LDK + sc] =
                *(const u16x8*)(Ahi + (size_t)(row0 + sm) * K + kt * 32 + sc);
            *(u16x8*)&As_l[sm * LDK + sc] =
                *(const u16x8*)(Alo + (size_t)(row0 + sm) * K + kt * 32 + sc);
        }
        // ---- stage B (already n-major, straight copy) ----
        *(u16x8*)&Bs_h[sm * LDK + sc] =
            *(const u16x8*)(Bhi + (size_t)(col0 + sm) * K + kt * 32 + sc);
        *(u16x8*)&Bs_l[sm * LDK + sc] =
            *(const u16x8*)(Blo + (size_t)(col0 + sm) * K + kt * 32 + sc);
        __syncthreads();

        // ---- MFMA ----
        bf16x8 a_h = *(const bf16x8*)&As_h[(w * 16 + nl) * LDK + q * 8];
        bf16x8 a_l = *(const bf16x8*)&As_l[(w * 16 + nl) * LDK + q * 8];
#pragma unroll
        for (int nt = 0; nt < 4; ++nt) {
            const int off = (nt * 16 + nl) * LDK + q * 8;
            bf16x8 b_h = *(const bf16x8*)&Bs_h[off];
            bf16x8 b_l = *(const bf16x8*)&Bs_l[off];
            acc[nt] = __builtin_amdgcn_mfma_f32_16x16x32_bf16(a_h, b_h, acc[nt], 0, 0, 0);
            acc[nt] = __builtin_amdgcn_mfma_f32_16x16x32_bf16(a_h, b_l, acc[nt], 0, 0, 0);
            acc[nt] = __builtin_amdgcn_mfma_f32_16x16x32_bf16(a_l, b_h, acc[nt], 0, 0, 0);
        }
        __syncthreads();
    }

    // ---- epilogue: bias + leaky_relu + split-store ----
#pragma unroll
    for (int nt = 0; nt < 4; ++nt) {
        const int col = col0 + nt * 16 + nl;
        const float b = bias[col];
#pragma unroll
        for (int r = 0; r < 4; ++r) {
            const int row = row0 + w * 16 + q * 4 + r;  // D: row=(lane>>4)*4+reg, col=lane&15
            float v = acc[nt][r] + b;
            v = v > 0.f ? v : 0.2f * v;
            unsigned short hi, lo; split2(v, hi, lo);
            Ohi[(size_t)row * HID + col] = hi;
            Olo[(size_t)row * HID + col] = lo;
        }
    }
}

// ---------------------------------------------------------------------------
// GEMM3 + update: st = h2 @ W3 + b3; s=2*tanh(st[:, :2048]); t=st[:, 2048:]
// x[:, iu] = x[:, iu]*exp(s) + t; log_det += sum(s).
// Block covers 64 rows x 64 s-columns (and the paired 64 t-columns).
// ---------------------------------------------------------------------------
__global__ __launch_bounds__(256) void gemm3_update(
    float* __restrict__ X,
    const unsigned short* __restrict__ Ahi, const unsigned short* __restrict__ Alo,
    const unsigned short* __restrict__ Whi, const unsigned short* __restrict__ Wlo, // [4096][256]
    const float* __restrict__ b3,   // [4096]
    float* __restrict__ logdet,     // [BATCH]
    int parity)
{
    __shared__ unsigned short As_h[64 * LDK], As_l[64 * LDK];
    __shared__ unsigned short Bs[4][64 * LDK];   // 0:s_hi 1:s_lo 2:t_hi 3:t_lo

    const int t = threadIdx.x;
    const int row0 = blockIdx.x * 64;
    const int n0   = blockIdx.y * 64;   // s-column tile base, [0,2048)
    const int w  = t >> 6;
    const int L  = t & 63;
    const int q  = L >> 4;
    const int nl = L & 15;
    const int sm = t >> 2;
    const int sc = (t & 3) * 8;

    f32x4 accS[4] = {{0,0,0,0},{0,0,0,0},{0,0,0,0},{0,0,0,0}};
    f32x4 accT[4] = {{0,0,0,0},{0,0,0,0},{0,0,0,0},{0,0,0,0}};

    const unsigned short* ah  = Ahi + (size_t)(row0 + sm) * HID;
    const unsigned short* al  = Alo + (size_t)(row0 + sm) * HID;
    const unsigned short* wsh = Whi + (size_t)(n0 + sm) * HID;
    const unsigned short* wsl = Wlo + (size_t)(n0 + sm) * HID;
    const unsigned short* wth = Whi + (size_t)(n0 + sm + NMASK) * HID;
    const unsigned short* wtl = Wlo + (size_t)(n0 + sm + NMASK) * HID;

    for (int kt = 0; kt < HID / 32; ++kt) {
        const int ko = kt * 32 + sc;
        *(u16x8*)&As_h[sm * LDK + sc]  = *(const u16x8*)(ah  + ko);
        *(u16x8*)&As_l[sm * LDK + sc]  = *(const u16x8*)(al  + ko);
        *(u16x8*)&Bs[0][sm * LDK + sc] = *(const u16x8*)(wsh + ko);
        *(u16x8*)&Bs[1][sm * LDK + sc] = *(const u16x8*)(wsl + ko);
        *(u16x8*)&Bs[2][sm * LDK + sc] = *(const u16x8*)(wth + ko);
        *(u16x8*)&Bs[3][sm * LDK + sc] = *(const u16x8*)(wtl + ko);
        __syncthreads();

        bf16x8 a_h = *(const bf16x8*)&As_h[(w * 16 + nl) * LDK + q * 8];
        bf16x8 a_l = *(const bf16x8*)&As_l[(w * 16 + nl) * LDK + q * 8];
#pragma unroll
        for (int nt = 0; nt < 4; ++nt) {
            const int off = (nt * 16 + nl) * LDK + q * 8;
            bf16x8 bsh = *(const bf16x8*)&Bs[0][off];
            bf16x8 bsl = *(const bf16x8*)&Bs[1][off];
            bf16x8 bth = *(const bf16x8*)&Bs[2][off];
            bf16x8 btl = *(const bf16x8*)&Bs[3][off];
            accS[nt] = __builtin_amdgcn_mfma_f32_16x16x32_bf16(a_h, bsh, accS[nt], 0, 0, 0);
            accS[nt] = __builtin_amdgcn_mfma_f32_16x16x32_bf16(a_h, bsl, accS[nt], 0, 0, 0);
            accS[nt] = __builtin_amdgcn_mfma_f32_16x16x32_bf16(a_l, bsh, accS[nt], 0, 0, 0);
            accT[nt] = __builtin_amdgcn_mfma_f32_16x16x32_bf16(a_h, bth, accT[nt], 0, 0, 0);
            accT[nt] = __builtin_amdgcn_mfma_f32_16x16x32_bf16(a_h, btl, accT[nt], 0, 0, 0);
            accT[nt] = __builtin_amdgcn_mfma_f32_16x16x32_bf16(a_l, bth, accT[nt], 0, 0, 0);
        }
        __syncthreads();
    }

    // ---- epilogue: s/t, x update, log_det ----
    float ldp[4] = {0.f, 0.f, 0.f, 0.f};
#pragma unroll
    for (int nt = 0; nt < 4; ++nt) {
        const int n   = n0 + nt * 16 + nl;         // s column / masked-order index
        const float bs = b3[n];
        const float bt = b3[n + NMASK];
        const int rsp = n >> 5;
        const int c   = n & 31;
        const int ucol = (rsp << 6) + 2 * c + ((rsp + parity + 1) & 1);
#pragma unroll
        for (int r = 0; r < 4; ++r) {
            const int row = row0 + w * 16 + q * 4 + r;
            float s  = 2.f * tanhf(accS[nt][r] + bs);
            float tt = accT[nt][r] + bt;
            float* xp = X + (size_t)row * NTOT + ucol;
            *xp = *xp * expf(s) + tt;
            ldp[r] += s;
        }
    }
    // reduce s over the 16 column-lanes, one atomicAdd per (row)
#pragma unroll
    for (int r = 0; r < 4; ++r) {
        float v = ldp[r];
        v += __shfl_xor(v, 1);
        v += __shfl_xor(v, 2);
        v += __shfl_xor(v, 4);
        v += __shfl_xor(v, 8);
        if (nl == 0) atomicAdd(&logdet[row0 + w * 16 + q * 4 + r], v);
    }
}

// ---------------------------------------------------------------------------
extern "C" void kernel_launch(void* const* d_in, const int* in_sizes, int n_in,
                              void* d_out, int out_size, void* d_ws, size_t ws_size,
                              hipStream_t stream)
{
    const float* z  = (const float*)d_in[0];
    const float* W1 = (const float*)d_in[1];
    const float* b1 = (const float*)d_in[2];
    const float* W2 = (const float*)d_in[3];
    const float* b2 = (const float*)d_in[4];
    const float* W3 = (const float*)d_in[5];
    const float* b3 = (const float*)d_in[6];

    float* xout   = (float*)d_out;
    float* logdet = xout + (size_t)BATCH * NTOT;

    // workspace layout (ushort elements)
    unsigned short* ws = (unsigned short*)d_ws;
    size_t o = 0;
    unsigned short* W1h = ws + o; o += (size_t)NLAYERS * HID * NMASK;
    unsigned short* W1l = ws + o; o += (size_t)NLAYERS * HID * NMASK;
    unsigned short* W2h = ws + o; o += (size_t)NLAYERS * HID * HID;
    unsigned short* W2l = ws + o; o += (size_t)NLAYERS * HID * HID;
    unsigned short* W3h = ws + o; o += (size_t)NLAYERS * NTOT * HID;
    unsigned short* W3l = ws + o; o += (size_t)NLAYERS * NTOT * HID;
    unsigned short* h1h = ws + o; o += (size_t)BATCH * HID;
    unsigned short* h1l = ws + o; o += (size_t)BATCH * HID;
    unsigned short* h2h = ws + o; o += (size_t)BATCH * HID;
    unsigned short* h2l = ws + o; o += (size_t)BATCH * HID;

    // x := z (output x region updated in place across layers); log_det := 0
    hipMemcpyAsync(xout, z, sizeof(float) * (size_t)BATCH * NTOT,
                   hipMemcpyDeviceToDevice, stream);
    hipMemsetAsync(logdet, 0, sizeof(float) * BATCH, stream);

    // pre-split + transpose all weights to n-major bf16 hi/lo
    split_transpose_kernel<<<dim3(NMASK / 32, HID / 32, NLAYERS), 256, 0, stream>>>(
        W1, W1h, W1l, NMASK, HID);
    split_transpose_kernel<<<dim3(HID / 32, HID / 32, NLAYERS), 256, 0, stream>>>(
        W2, W2h, W2l, HID, HID);
    split_transpose_kernel<<<dim3(HID / 32, NTOT / 32, NLAYERS), 256, 0, stream>>>(
        W3, W3h, W3l, HID, NTOT);

    for (int i = 0; i < NLAYERS; ++i) {
        const int parity = i & 1;
        gemm_h<true><<<dim3(BATCH / 64, HID / 64), 256, 0, stream>>>(
            xout, nullptr, nullptr,
            W1h + (size_t)i * HID * NMASK, W1l + (size_t)i * HID * NMASK,
            b1 + (size_t)i * HID,
            h1h, h1l, NMASK, parity);
        gemm_h<false><<<dim3(BATCH / 64, HID / 64), 256, 0, stream>>>(
            nullptr, h1h, h1l,
            W2h + (size_t)i * HID * HID, W2l + (size_t)i * HID * HID,
            b2 + (size_t)i * HID,
            h2h, h2l, HID, parity);
        gemm3_update<<<dim3(BATCH / 64, NMASK / 64), 256, 0, stream>>>(
            xout, h2h, h2l,
            W3h + (size_t)i * NTOT * HID, W3l + (size_t)i * NTOT * HID,
            b3 + (size_t)i * NTOT,
            logdet, parity);
    }
}

// Round 2
// 1798.998 us; speedup vs baseline: 1.0996x; 1.0996x over previous
//
#include <hip/hip_runtime.h>
#include <stdint.h>

#define BATCH   8192
#define NTOT    4096
#define HID     256
#define NLAYERS 8
#define NMASK   2048
#define HALF    ((size_t)BATCH * NMASK)   // elements per checkerboard half

typedef unsigned short ushort_t;
typedef float  f32x4  __attribute__((ext_vector_type(4)));
typedef __bf16 bf16x8 __attribute__((ext_vector_type(8)));
typedef unsigned short u16x4 __attribute__((ext_vector_type(4)));

__device__ __forceinline__ unsigned short f2bf(float f) {
    union { float f; unsigned u; } v; v.f = f;
    unsigned r = v.u + 0x7FFFu + ((v.u >> 16) & 1u);
    return (unsigned short)(r >> 16);
}
__device__ __forceinline__ float bf2f(unsigned short h) {
    union { float f; unsigned u; } v; v.u = ((unsigned)h) << 16;
    return v.f;
}
__device__ __forceinline__ void split2(float f, unsigned short& hi, unsigned short& lo) {
    hi = f2bf(f);
    lo = f2bf(f - bf2f(hi));
}
// async global->LDS, 16B per lane. LDS dest must be lane-affine (base + lane*16).
__device__ __forceinline__ void async16(const void* g, void* l) {
    __builtin_amdgcn_global_load_lds(
        (const __attribute__((address_space(1))) unsigned int*)g,
        (__attribute__((address_space(3))) unsigned int*)l, 16, 0, 0);
}

// ---------------------------------------------------------------------------
// Weight transpose + bf16 hi/lo split: in [NL][K][N] fp32 -> out [NL][N][K]
// ---------------------------------------------------------------------------
__global__ __launch_bounds__(256) void split_transpose_kernel(
    const float* __restrict__ W,
    ushort_t* __restrict__ Whi, ushort_t* __restrict__ Wlo,
    int K, int N)
{
    __shared__ float tile[32][33];
    const int l  = blockIdx.z;
    const int k0 = blockIdx.x * 32;
    const int n0 = blockIdx.y * 32;
    const float* Wl = W + (size_t)l * K * N;
    const int tx = threadIdx.x & 31;
    const int ty = threadIdx.x >> 5;
#pragma unroll
    for (int it = 0; it < 4; ++it) {
        int r = ty + it * 8;
        tile[r][tx] = Wl[(size_t)(k0 + r) * N + (n0 + tx)];
    }
    __syncthreads();
    const size_t obase = (size_t)l * N * K;
#pragma unroll
    for (int it = 0; it < 4; ++it) {
        int r = ty + it * 8;
        float v = tile[tx][r];
        unsigned short hi, lo; split2(v, hi, lo);
        size_t oi = obase + (size_t)(n0 + r) * K + (k0 + tx);
        Whi[oi] = hi; Wlo[oi] = lo;
    }
}

// ---------------------------------------------------------------------------
// prep: z -> dense masked-ordered hi/lo splits for both checkerboard halves.
// half q at col(n,q) = 64*rsp + 2*c + ((rsp+q)&1), n = 32*rsp + c.
// ---------------------------------------------------------------------------
__global__ __launch_bounds__(256) void prep_split(
    const float* __restrict__ z,
    ushort_t* __restrict__ xsh, ushort_t* __restrict__ xsl)
{
    size_t f = (((size_t)blockIdx.x * 256) + threadIdx.x) * 4;  // pair base index
    int row = (int)(f >> 11);
    int n   = (int)(f & 2047);
    int sel = (n >> 5) & 1;                 // rsp parity (uniform over 4 pairs)
    const float4* zp = (const float4*)(z + (size_t)row * NTOT + 2 * (size_t)n);
    float4 z01 = zp[0], z23 = zp[1];
    float e[8] = {z01.x, z01.y, z01.z, z01.w, z23.x, z23.y, z23.z, z23.w};
    u16x4 ah, al, bh, bl;
#pragma unroll
    for (int i = 0; i < 4; ++i) {
        float c0 = e[2 * i], c1 = e[2 * i + 1];
        float a = sel ? c1 : c0;            // half 0
        float b = sel ? c0 : c1;            // half 1
        unsigned short h, l;
        split2(a, h, l); ah[i] = h; al[i] = l;
        split2(b, h, l); bh[i] = h; bl[i] = l;
    }
    size_t off = (size_t)row * NMASK + n;
    *(u16x4*)&xsh[off] = ah;        *(u16x4*)&xsl[off] = al;
    *(u16x4*)&xsh[HALF + off] = bh; *(u16x4*)&xsl[HALF + off] = bl;
}

// ---------------------------------------------------------------------------
// finalize: dense hi/lo splits (both halves) -> fp32 x in natural layout
// ---------------------------------------------------------------------------
__global__ __launch_bounds__(256) void finalize_x(
    const ushort_t* __restrict__ xsh, const ushort_t* __restrict__ xsl,
    float* __restrict__ xout)
{
    size_t f = (((size_t)blockIdx.x * 256) + threadIdx.x) * 4;
    int row = (int)(f >> 11);
    int n   = (int)(f & 2047);
    int sel = (n >> 5) & 1;
    size_t off = (size_t)row * NMASK + n;
    u16x4 ah = *(const u16x4*)&xsh[off],        al = *(const u16x4*)&xsl[off];
    u16x4 bh = *(const u16x4*)&xsh[HALF + off], bl = *(const u16x4*)&xsl[HALF + off];
    float o[8];
#pragma unroll
    for (int i = 0; i < 4; ++i) {
        float va = bf2f(ah[i]) + bf2f(al[i]);
        float vb = bf2f(bh[i]) + bf2f(bl[i]);
        o[2 * i]     = sel ? vb : va;
        o[2 * i + 1] = sel ? va : vb;
    }
    float* op = xout + (size_t)row * NTOT + 2 * (size_t)n;
    ((float4*)op)[0] = make_float4(o[0], o[1], o[2], o[3]);
    ((float4*)op)[1] = make_float4(o[4], o[5], o[6], o[7]);
}

// ---------------------------------------------------------------------------
// gemm128: 128x128 tile, triple-bf16 (hi*hi + hi*lo + lo*hi), K-tile 32,
// global_load_lds staging, 4 waves (2x2), each wave 4x4 16x16x32 MFMA tiles.
// MODE 0: store raw fp32 partial to Pout (+ blockIdx.z * M*256) [split-K]
// MODE 1: bias + leaky_relu + hi/lo split store to Ohi/Olo (row stride 256)
// ---------------------------------------------------------------------------
template<int MODE>
__global__ __launch_bounds__(256) void gemm128(
    const ushort_t* __restrict__ Ahi, const ushort_t* __restrict__ Alo, int lda,
    const ushort_t* __restrict__ Bhi, const ushort_t* __restrict__ Blo, int ldb,
    int nk,
    float* __restrict__ Pout,
    const float* __restrict__ bias,
    ushort_t* __restrict__ Ohi, ushort_t* __restrict__ Olo)
{
    __shared__ __align__(16) ushort_t Ah[128 * 32], Al[128 * 32];
    __shared__ __align__(16) ushort_t Bh[128 * 32], Bl[128 * 32];

    const int t = threadIdx.x;
    const int row0 = blockIdx.x * 128;
    const int col0 = blockIdx.y * 128;
    const int k0   = blockIdx.z * nk * 32;
    const int w  = t >> 6, L = t & 63;
    const int q  = L >> 4, nl = L & 15;
    const int wr = w >> 1, wc = w & 1;

    f32x4 acc[4][4] = {};

    for (int kt = 0; kt < nk; ++kt) {
        const int kk = k0 + kt * 32;
#pragma unroll
        for (int pass = 0; pass < 2; ++pass) {
            const int chunk = t + pass * 256;
            const int r  = chunk >> 2;
            const int ko = (chunk & 3) * 8;
            async16(Ahi + (size_t)(row0 + r) * lda + kk + ko, (char*)Ah + chunk * 16);
            async16(Alo + (size_t)(row0 + r) * lda + kk + ko, (char*)Al + chunk * 16);
            async16(Bhi + (size_t)(col0 + r) * ldb + kk + ko, (char*)Bh + chunk * 16);
            async16(Blo + (size_t)(col0 + r) * ldb + kk + ko, (char*)Bl + chunk * 16);
        }
        __syncthreads();

        bf16x8 a_h[4], a_l[4];
#pragma unroll
        for (int mt = 0; mt < 4; ++mt) {
            const int r = wr * 64 + mt * 16 + nl;
            a_h[mt] = *(const bf16x8*)&Ah[r * 32 + q * 8];
            a_l[mt] = *(const bf16x8*)&Al[r * 32 + q * 8];
        }
#pragma unroll
        for (int nt = 0; nt < 4; ++nt) {
            const int c = wc * 64 + nt * 16 + nl;
            bf16x8 b_h = *(const bf16x8*)&Bh[c * 32 + q * 8];
            bf16x8 b_l = *(const bf16x8*)&Bl[c * 32 + q * 8];
#pragma unroll
            for (int mt = 0; mt < 4; ++mt) {
                acc[mt][nt] = __builtin_amdgcn_mfma_f32_16x16x32_bf16(a_h[mt], b_h, acc[mt][nt], 0, 0, 0);
                acc[mt][nt] = __builtin_amdgcn_mfma_f32_16x16x32_bf16(a_h[mt], b_l, acc[mt][nt], 0, 0, 0);
                acc[mt][nt] = __builtin_amdgcn_mfma_f32_16x16x32_bf16(a_l[mt], b_h, acc[mt][nt], 0, 0, 0);
            }
        }
        __syncthreads();
    }

    if (MODE == 0) {
        float* out = Pout + (size_t)blockIdx.z * BATCH * HID;
#pragma unroll
        for (int mt = 0; mt < 4; ++mt)
#pragma unroll
            for (int r = 0; r < 4; ++r) {
                const int row = row0 + wr * 64 + mt * 16 + q * 4 + r;
                float* op = out + (size_t)row * HID + col0 + wc * 64 + nl;
#pragma unroll
                for (int nt = 0; nt < 4; ++nt)
                    op[nt * 16] = acc[mt][nt][r];
            }
    } else {
#pragma unroll
        for (int mt = 0; mt < 4; ++mt)
#pragma unroll
            for (int nt = 0; nt < 4; ++nt) {
                const int col = col0 + wc * 64 + nt * 16 + nl;
                const float bv = bias[col];
#pragma unroll
                for (int r = 0; r < 4; ++r) {
                    const int row = row0 + wr * 64 + mt * 16 + q * 4 + r;
                    float v = acc[mt][nt][r] + bv;
                    v = v > 0.f ? v : 0.2f * v;
                    unsigned short hh, ll; split2(v, hh, ll);
                    Ohi[(size_t)row * HID + col] = hh;
                    Olo[(size_t)row * HID + col] = ll;
                }
            }
    }
}

// ---------------------------------------------------------------------------
// combine split-K partials: h1 = leaky(P0 + P1 + b1), hi/lo split store
// ---------------------------------------------------------------------------
__global__ __launch_bounds__(256) void combine_leaky(
    const float* __restrict__ P, const float* __restrict__ bias,
    ushort_t* __restrict__ Ohi, ushort_t* __restrict__ Olo)
{
    size_t f = (((size_t)blockIdx.x * 256) + threadIdx.x) * 4;
    const int col = (int)(f & (HID - 1));
    float4 p0 = *(const float4*)&P[f];
    float4 p1 = *(const float4*)&P[(size_t)BATCH * HID + f];
    float4 bv = *(const float4*)&bias[col];
    float v[4] = {p0.x + p1.x + bv.x, p0.y + p1.y + bv.y,
                  p0.z + p1.z + bv.z, p0.w + p1.w + bv.w};
    u16x4 h, l;
#pragma unroll
    for (int i = 0; i < 4; ++i) {
        float vv = v[i] > 0.f ? v[i] : 0.2f * v[i];
        unsigned short hh, ll; split2(vv, hh, ll);
        h[i] = hh; l[i] = ll;
    }
    *(u16x4*)&Ohi[f] = h;
    *(u16x4*)&Olo[f] = l;
}

// ---------------------------------------------------------------------------
// gemm3_update: st = h2 @ W3 + b3 for 128 rows x 64 s-cols (+ paired t-cols);
// s = 2*tanh(.); new = old*exp(s)+t written in place to the dense split buffer
// (half q1) -- which is also the next layer's gemm1 A operand. logdet += sum s.
// ---------------------------------------------------------------------------
__global__ __launch_bounds__(256) void gemm3_update(
    const ushort_t* __restrict__ Ahi, const ushort_t* __restrict__ Alo,  // h2 splits [B][256]
    const ushort_t* __restrict__ Whi, const ushort_t* __restrict__ Wlo,  // W3 n-major [4096][256]
    const float* __restrict__ b3,                                        // [4096]
    ushort_t* __restrict__ xsh, ushort_t* __restrict__ xsl,              // [2][B][2048]
    float* __restrict__ logdet, int q1)
{
    __shared__ __align__(16) ushort_t Ah[128 * 32], Al[128 * 32];
    __shared__ __align__(16) ushort_t Bsh[64 * 32], Bsl[64 * 32];
    __shared__ __align__(16) ushort_t Bth[64 * 32], Btl[64 * 32];

    const int t = threadIdx.x;
    const int row0 = blockIdx.x * 128;
    const int n0   = blockIdx.y * 64;
    const int w  = t >> 6, L = t & 63;
    const int q  = L >> 4, nl = L & 15;
    const int wr = w >> 1, wc = w & 1;

    f32x4 accS[4][2] = {};
    f32x4 accT[4][2] = {};

    for (int kt = 0; kt < HID / 32; ++kt) {
        const int kk = kt * 32;
#pragma unroll
        for (int pass = 0; pass < 2; ++pass) {
            const int chunk = t + pass * 256;
            const int r  = chunk >> 2;
            const int ko = (chunk & 3) * 8;
            async16(Ahi + (size_t)(row0 + r) * HID + kk + ko, (char*)Ah + chunk * 16);
            async16(Alo + (size_t)(row0 + r) * HID + kk + ko, (char*)Al + chunk * 16);
        }
        {
            const int r  = t >> 2;
            const int ko = (t & 3) * 8;
            const size_t gs = (size_t)(n0 + r) * HID + kk + ko;
            async16(Whi + gs, (char*)Bsh + t * 16);
            async16(Wlo + gs, (char*)Bsl + t * 16);
            async16(Whi + (size_t)NMASK * HID + gs, (char*)Bth + t * 16);
            async16(Wlo + (size_t)NMASK * HID + gs, (char*)Btl + t * 16);
        }
        __syncthreads();

        bf16x8 a_h[4], a_l[4];
#pragma unroll
        for (int mt = 0; mt < 4; ++mt) {
            const int r = wr * 64 + mt * 16 + nl;
            a_h[mt] = *(const bf16x8*)&Ah[r * 32 + q * 8];
            a_l[mt] = *(const bf16x8*)&Al[r * 32 + q * 8];
        }
#pragma unroll
        for (int nt = 0; nt < 2; ++nt) {
            const int c = wc * 32 + nt * 16 + nl;
            bf16x8 bs_h = *(const bf16x8*)&Bsh[c * 32 + q * 8];
            bf16x8 bs_l = *(const bf16x8*)&Bsl[c * 32 + q * 8];
            bf16x8 bt_h = *(const bf16x8*)&Bth[c * 32 + q * 8];
            bf16x8 bt_l = *(const bf16x8*)&Btl[c * 32 + q * 8];
#pragma unroll
            for (int mt = 0; mt < 4; ++mt) {
                accS[mt][nt] = __builtin_amdgcn_mfma_f32_16x16x32_bf16(a_h[mt], bs_h, accS[mt][nt], 0, 0, 0);
                accS[mt][nt] = __builtin_amdgcn_mfma_f32_16x16x32_bf16(a_h[mt], bs_l, accS[mt][nt], 0, 0, 0);
                accS[mt][nt] = __builtin_amdgcn_mfma_f32_16x16x32_bf16(a_l[mt], bs_h, accS[mt][nt], 0, 0, 0);
                accT[mt][nt] = __builtin_amdgcn_mfma_f32_16x16x32_bf16(a_h[mt], bt_h, accT[mt][nt], 0, 0, 0);
                accT[mt][nt] = __builtin_amdgcn_mfma_f32_16x16x32_bf16(a_h[mt], bt_l, accT[mt][nt], 0, 0, 0);
                accT[mt][nt] = __builtin_amdgcn_mfma_f32_16x16x32_bf16(a_l[mt], bt_h, accT[mt][nt], 0, 0, 0);
            }
        }
        __syncthreads();
    }

    // ---- epilogue ----
    ushort_t* xh = xsh + (size_t)q1 * HALF;
    ushort_t* xl = xsl + (size_t)q1 * HALF;
    float ld[4][4] = {};
#pragma unroll
    for (int mt = 0; mt < 4; ++mt) {
#pragma unroll
        for (int nt = 0; nt < 2; ++nt) {
            const int n  = n0 + wc * 32 + nt * 16 + nl;
            const float bs = b3[n];
            const float bt = b3[n + NMASK];
#pragma unroll
            for (int r = 0; r < 4; ++r) {
                const int row = row0 + wr * 64 + mt * 16 + q * 4 + r;
                const float sv = accS[mt][nt][r] + bs;
                // overflow-safe 2*tanh(sv) via fast exp
                const float e2 = __expf(-2.f * fabsf(sv));
                float th = __fdividef(1.f - e2, 1.f + e2);
                th = __builtin_copysignf(th, sv);
                const float s  = 2.f * th;
                const float es = __expf(s);
                const size_t off = (size_t)row * NMASK + n;
                const float old = bf2f(xh[off]) + bf2f(xl[off]);
                const float nv  = old * es + accT[mt][nt][r] + bt;
                unsigned short hh, ll; split2(nv, hh, ll);
                xh[off] = hh; xl[off] = ll;
                ld[mt][r] += s;
            }
        }
    }
#pragma unroll
    for (int mt = 0; mt < 4; ++mt)
#pragma unroll
        for (int r = 0; r < 4; ++r) {
            float v = ld[mt][r];
            v += __shfl_xor(v, 1);
            v += __shfl_xor(v, 2);
            v += __shfl_xor(v, 4);
            v += __shfl_xor(v, 8);
            if (nl == 0)
                atomicAdd(&logdet[row0 + wr * 64 + mt * 16 + q * 4 + r], v);
        }
}

// ---------------------------------------------------------------------------
extern "C" void kernel_launch(void* const* d_in, const int* in_sizes, int n_in,
                              void* d_out, int out_size, void* d_ws, size_t ws_size,
                              hipStream_t stream)
{
    const float* z  = (const float*)d_in[0];
    const float* W1 = (const float*)d_in[1];
    const float* b1 = (const float*)d_in[2];
    const float* W2 = (const float*)d_in[3];
    const float* b2 = (const float*)d_in[4];
    const float* W3 = (const float*)d_in[5];
    const float* b3 = (const float*)d_in[6];

    float* xout   = (float*)d_out;
    float* logdet = xout + (size_t)BATCH * NTOT;

    // workspace layout (u16 elements, then fp32 partials) -- ~220 MB total
    ushort_t* ws = (ushort_t*)d_ws;
    size_t o = 0;
    ushort_t* W1h = ws + o; o += (size_t)NLAYERS * HID * NMASK;
    ushort_t* W1l = ws + o; o += (size_t)NLAYERS * HID * NMASK;
    ushort_t* W2h = ws + o; o += (size_t)NLAYERS * HID * HID;
    ushort_t* W2l = ws + o; o += (size_t)NLAYERS * HID * HID;
    ushort_t* W3h = ws + o; o += (size_t)NLAYERS * NTOT * HID;
    ushort_t* W3l = ws + o; o += (size_t)NLAYERS * NTOT * HID;
    ushort_t* h1h = ws + o; o += (size_t)BATCH * HID;
    ushort_t* h1l = ws + o; o += (size_t)BATCH * HID;
    ushort_t* h2h = ws + o; o += (size_t)BATCH * HID;
    ushort_t* h2l = ws + o; o += (size_t)BATCH * HID;
    ushort_t* xsh = ws + o; o += 2 * HALF;
    ushort_t* xsl = ws + o; o += 2 * HALF;
    float*    P   = (float*)(ws + o);   // [2][BATCH][HID] fp32 split-K partials

    hipMemsetAsync(logdet, 0, sizeof(float) * BATCH, stream);

    // weights: transpose to n-major + hi/lo split
    split_transpose_kernel<<<dim3(NMASK / 32, HID / 32, NLAYERS), 256, 0, stream>>>(
        W1, W1h, W1l, NMASK, HID);
    split_transpose_kernel<<<dim3(HID / 32, HID / 32, NLAYERS), 256, 0, stream>>>(
        W2, W2h, W2l, HID, HID);
    split_transpose_kernel<<<dim3(HID / 32, NTOT / 32, NLAYERS), 256, 0, stream>>>(
        W3, W3h, W3l, HID, NTOT);

    // z -> dense masked-ordered hi/lo splits for both halves
    prep_split<<<dim3((unsigned)(HALF / 4 / 256)), 256, 0, stream>>>(z, xsh, xsl);

    for (int i = 0; i < NLAYERS; ++i) {
        const int p  = i & 1;      // masked half
        const int q1 = 1 - p;      // updated half
        // gemm1 (split-K=2): P[ks] = xm @ W1  (M=8192,N=256,K=2048)
        gemm128<0><<<dim3(BATCH / 128, HID / 128, 2), 256, 0, stream>>>(
            xsh + (size_t)p * HALF, xsl + (size_t)p * HALF, NMASK,
            W1h + (size_t)i * HID * NMASK, W1l + (size_t)i * HID * NMASK, NMASK,
            32, P, nullptr, nullptr, nullptr);
        combine_leaky<<<dim3((unsigned)((size_t)BATCH * HID / 4 / 256)), 256, 0, stream>>>(
            P, b1 + (size_t)i * HID, h1h, h1l);
        // gemm2: h2 = leaky(h1 @ W2 + b2)  (K=256)
        gemm128<1><<<dim3(BATCH / 128, HID / 128, 1), 256, 0, stream>>>(
            h1h, h1l, HID,
            W2h + (size_t)i * HID * HID, W2l + (size_t)i * HID * HID, HID,
            8, nullptr, b2 + (size_t)i * HID, h2h, h2l);
        // gemm3 + coupling update (writes next layer's masked splits in place)
        gemm3_update<<<dim3(BATCH / 128, NMASK / 64), 256, 0, stream>>>(
            h2h, h2l,
            W3h + (size_t)i * NTOT * HID, W3l + (size_t)i * NTOT * HID,
            b3 + (size_t)i * NTOT,
            xsh, xsl, logdet, q1);
    }

    finalize_x<<<dim3((unsigned)(HALF / 4 / 256)), 256, 0, stream>>>(xsh, xsl, xout);
}

// Round 3
// 1598.264 us; speedup vs baseline: 1.2377x; 1.1256x over previous
//
#include <hip/hip_runtime.h>
#include <stdint.h>

#define BATCH   8192
#define NTOT    4096
#define HID     256
#define NLAYERS 8
#define NMASK   2048
#define HALF    ((size_t)BATCH * NMASK)   // elements per checkerboard half

typedef unsigned short ushort_t;
typedef float  f32x4  __attribute__((ext_vector_type(4)));
typedef __bf16 bf16x8 __attribute__((ext_vector_type(8)));
typedef unsigned short u16x4 __attribute__((ext_vector_type(4)));

__device__ __forceinline__ unsigned short f2bf(float f) {
    union { float f; unsigned u; } v; v.f = f;
    unsigned r = v.u + 0x7FFFu + ((v.u >> 16) & 1u);
    return (unsigned short)(r >> 16);
}
__device__ __forceinline__ float bf2f(unsigned short h) {
    union { float f; unsigned u; } v; v.u = ((unsigned)h) << 16;
    return v.f;
}
__device__ __forceinline__ void split2(float f, unsigned short& hi, unsigned short& lo) {
    hi = f2bf(f);
    lo = f2bf(f - bf2f(hi));
}
// async global->LDS, 16B per lane. LDS dest must be lane-affine (base + lane*16).
__device__ __forceinline__ void async16(const void* g, void* l) {
    __builtin_amdgcn_global_load_lds(
        (const __attribute__((address_space(1))) unsigned int*)g,
        (__attribute__((address_space(3))) unsigned int*)l, 16, 0, 0);
}

// ---------------------------------------------------------------------------
// Weight transpose + bf16 hi/lo split: in [NL][K][N] fp32 -> out [NL][N][K]
// ---------------------------------------------------------------------------
__global__ __launch_bounds__(256) void split_transpose_kernel(
    const float* __restrict__ W,
    ushort_t* __restrict__ Whi, ushort_t* __restrict__ Wlo,
    int K, int N)
{
    __shared__ float tile[32][33];
    const int l  = blockIdx.z;
    const int k0 = blockIdx.x * 32;
    const int n0 = blockIdx.y * 32;
    const float* Wl = W + (size_t)l * K * N;
    const int tx = threadIdx.x & 31;
    const int ty = threadIdx.x >> 5;
#pragma unroll
    for (int it = 0; it < 4; ++it) {
        int r = ty + it * 8;
        tile[r][tx] = Wl[(size_t)(k0 + r) * N + (n0 + tx)];
    }
    __syncthreads();
    const size_t obase = (size_t)l * N * K;
#pragma unroll
    for (int it = 0; it < 4; ++it) {
        int r = ty + it * 8;
        float v = tile[tx][r];
        unsigned short hi, lo; split2(v, hi, lo);
        size_t oi = obase + (size_t)(n0 + r) * K + (k0 + tx);
        Whi[oi] = hi; Wlo[oi] = lo;
    }
}

// ---------------------------------------------------------------------------
// prep: z -> dense masked-ordered hi/lo splits for both checkerboard halves.
// half q at col(n,q) = 64*rsp + 2*c + ((rsp+q)&1), n = 32*rsp + c.
// ---------------------------------------------------------------------------
__global__ __launch_bounds__(256) void prep_split(
    const float* __restrict__ z,
    ushort_t* __restrict__ xsh, ushort_t* __restrict__ xsl)
{
    size_t f = (((size_t)blockIdx.x * 256) + threadIdx.x) * 4;  // pair base index
    int row = (int)(f >> 11);
    int n   = (int)(f & 2047);
    int sel = (n >> 5) & 1;                 // rsp parity (uniform over 4 pairs)
    const float4* zp = (const float4*)(z + (size_t)row * NTOT + 2 * (size_t)n);
    float4 z01 = zp[0], z23 = zp[1];
    float e[8] = {z01.x, z01.y, z01.z, z01.w, z23.x, z23.y, z23.z, z23.w};
    u16x4 ah, al, bh, bl;
#pragma unroll
    for (int i = 0; i < 4; ++i) {
        float c0 = e[2 * i], c1 = e[2 * i + 1];
        float a = sel ? c1 : c0;            // half 0
        float b = sel ? c0 : c1;            // half 1
        unsigned short h, l;
        split2(a, h, l); ah[i] = h; al[i] = l;
        split2(b, h, l); bh[i] = h; bl[i] = l;
    }
    size_t off = (size_t)row * NMASK + n;
    *(u16x4*)&xsh[off] = ah;        *(u16x4*)&xsl[off] = al;
    *(u16x4*)&xsh[HALF + off] = bh; *(u16x4*)&xsl[HALF + off] = bl;
}

// ---------------------------------------------------------------------------
// finalize: dense hi/lo splits (both halves) -> fp32 x in natural layout
// ---------------------------------------------------------------------------
__global__ __launch_bounds__(256) void finalize_x(
    const ushort_t* __restrict__ xsh, const ushort_t* __restrict__ xsl,
    float* __restrict__ xout)
{
    size_t f = (((size_t)blockIdx.x * 256) + threadIdx.x) * 4;
    int row = (int)(f >> 11);
    int n   = (int)(f & 2047);
    int sel = (n >> 5) & 1;
    size_t off = (size_t)row * NMASK + n;
    u16x4 ah = *(const u16x4*)&xsh[off],        al = *(const u16x4*)&xsl[off];
    u16x4 bh = *(const u16x4*)&xsh[HALF + off], bl = *(const u16x4*)&xsl[HALF + off];
    float o[8];
#pragma unroll
    for (int i = 0; i < 4; ++i) {
        float va = bf2f(ah[i]) + bf2f(al[i]);
        float vb = bf2f(bh[i]) + bf2f(bl[i]);
        o[2 * i]     = sel ? vb : va;
        o[2 * i + 1] = sel ? va : vb;
    }
    float* op = xout + (size_t)row * NTOT + 2 * (size_t)n;
    ((float4*)op)[0] = make_float4(o[0], o[1], o[2], o[3]);
    ((float4*)op)[1] = make_float4(o[4], o[5], o[6], o[7]);
}

// ---------------------------------------------------------------------------
// gemm_splitk: 128x128 tile, triple-bf16, K-tile 32, global_load_lds staging.
// Stores raw fp32 partial to Pout + blockIdx.z * BATCH*HID.
// ---------------------------------------------------------------------------
__global__ __launch_bounds__(256) void gemm_splitk(
    const ushort_t* __restrict__ Ahi, const ushort_t* __restrict__ Alo, int lda,
    const ushort_t* __restrict__ Bhi, const ushort_t* __restrict__ Blo, int ldb,
    int nk,
    float* __restrict__ Pout)
{
    __shared__ __align__(16) ushort_t Ah[128 * 32], Al[128 * 32];
    __shared__ __align__(16) ushort_t Bh[128 * 32], Bl[128 * 32];

    const int t = threadIdx.x;
    const int row0 = blockIdx.x * 128;
    const int col0 = blockIdx.y * 128;
    const int k0   = blockIdx.z * nk * 32;
    const int w  = t >> 6, L = t & 63;
    const int q  = L >> 4, nl = L & 15;
    const int wr = w >> 1, wc = w & 1;

    f32x4 acc[4][4] = {};

    for (int kt = 0; kt < nk; ++kt) {
        const int kk = k0 + kt * 32;
#pragma unroll
        for (int pass = 0; pass < 2; ++pass) {
            const int chunk = t + pass * 256;
            const int r  = chunk >> 2;
            const int ko = (chunk & 3) * 8;
            async16(Ahi + (size_t)(row0 + r) * lda + kk + ko, (char*)Ah + chunk * 16);
            async16(Alo + (size_t)(row0 + r) * lda + kk + ko, (char*)Al + chunk * 16);
            async16(Bhi + (size_t)(col0 + r) * ldb + kk + ko, (char*)Bh + chunk * 16);
            async16(Blo + (size_t)(col0 + r) * ldb + kk + ko, (char*)Bl + chunk * 16);
        }
        __syncthreads();

        bf16x8 a_h[4], a_l[4];
#pragma unroll
        for (int mt = 0; mt < 4; ++mt) {
            const int r = wr * 64 + mt * 16 + nl;
            a_h[mt] = *(const bf16x8*)&Ah[r * 32 + q * 8];
            a_l[mt] = *(const bf16x8*)&Al[r * 32 + q * 8];
        }
#pragma unroll
        for (int nt = 0; nt < 4; ++nt) {
            const int c = wc * 64 + nt * 16 + nl;
            bf16x8 b_h = *(const bf16x8*)&Bh[c * 32 + q * 8];
            bf16x8 b_l = *(const bf16x8*)&Bl[c * 32 + q * 8];
#pragma unroll
            for (int mt = 0; mt < 4; ++mt) {
                acc[mt][nt] = __builtin_amdgcn_mfma_f32_16x16x32_bf16(a_h[mt], b_h, acc[mt][nt], 0, 0, 0);
                acc[mt][nt] = __builtin_amdgcn_mfma_f32_16x16x32_bf16(a_h[mt], b_l, acc[mt][nt], 0, 0, 0);
                acc[mt][nt] = __builtin_amdgcn_mfma_f32_16x16x32_bf16(a_l[mt], b_h, acc[mt][nt], 0, 0, 0);
            }
        }
        __syncthreads();
    }

    float* out = Pout + (size_t)blockIdx.z * BATCH * HID;
#pragma unroll
    for (int mt = 0; mt < 4; ++mt)
#pragma unroll
        for (int r = 0; r < 4; ++r) {
            const int row = row0 + wr * 64 + mt * 16 + q * 4 + r;
            float* op = out + (size_t)row * HID + col0 + wc * 64 + nl;
#pragma unroll
            for (int nt = 0; nt < 4; ++nt)
                op[nt * 16] = acc[mt][nt][r];
        }
}

// ---------------------------------------------------------------------------
// combine split-K partials: O = leaky(sum_j P[j] + bias), hi/lo split store
// ---------------------------------------------------------------------------
__global__ __launch_bounds__(256) void combine_leaky(
    const float* __restrict__ P, int np, const float* __restrict__ bias,
    ushort_t* __restrict__ Ohi, ushort_t* __restrict__ Olo)
{
    size_t f = (((size_t)blockIdx.x * 256) + threadIdx.x) * 4;
    const int col = (int)(f & (HID - 1));
    float4 a = *(const float4*)&P[f];
    for (int j = 1; j < np; ++j) {
        float4 p = *(const float4*)&P[(size_t)j * BATCH * HID + f];
        a.x += p.x; a.y += p.y; a.z += p.z; a.w += p.w;
    }
    float4 bv = *(const float4*)&bias[col];
    float v[4] = {a.x + bv.x, a.y + bv.y, a.z + bv.z, a.w + bv.w};
    u16x4 h, l;
#pragma unroll
    for (int i = 0; i < 4; ++i) {
        float vv = v[i] > 0.f ? v[i] : 0.2f * v[i];
        unsigned short hh, ll; split2(vv, hh, ll);
        h[i] = hh; l[i] = ll;
    }
    *(u16x4*)&Ohi[f] = h;
    *(u16x4*)&Olo[f] = l;
}

// ---------------------------------------------------------------------------
// gemm3_update: st = h2 @ W3 + b3 for 128 rows x 128 s-cols (+ paired t-cols);
// s = 2*tanh(.); new = old*exp(s)+t written in place to the dense split buffer
// (half q1) -- which is also the next layer's gemm1 A operand. logdet += sum s.
// ---------------------------------------------------------------------------
__global__ __launch_bounds__(256, 2) void gemm3_update(
    const ushort_t* __restrict__ Ahi, const ushort_t* __restrict__ Alo,  // h2 splits [B][256]
    const ushort_t* __restrict__ Whi, const ushort_t* __restrict__ Wlo,  // W3 n-major [4096][256]
    const float* __restrict__ b3,                                        // [4096]
    ushort_t* __restrict__ xsh, ushort_t* __restrict__ xsl,              // [2][B][2048]
    float* __restrict__ logdet, int q1)
{
    __shared__ __align__(16) ushort_t Ah[128 * 32], Al[128 * 32];
    __shared__ __align__(16) ushort_t Bsh[128 * 32], Bsl[128 * 32];
    __shared__ __align__(16) ushort_t Bth[128 * 32], Btl[128 * 32];

    const int t = threadIdx.x;
    const int row0 = blockIdx.x * 128;
    const int n0   = blockIdx.y * 128;
    const int w  = t >> 6, L = t & 63;
    const int q  = L >> 4, nl = L & 15;
    const int wr = w >> 1, wc = w & 1;

    f32x4 accS[4][4] = {};
    f32x4 accT[4][4] = {};

    for (int kt = 0; kt < HID / 32; ++kt) {
        const int kk = kt * 32;
#pragma unroll
        for (int pass = 0; pass < 2; ++pass) {
            const int chunk = t + pass * 256;
            const int r  = chunk >> 2;
            const int ko = (chunk & 3) * 8;
            async16(Ahi + (size_t)(row0 + r) * HID + kk + ko, (char*)Ah + chunk * 16);
            async16(Alo + (size_t)(row0 + r) * HID + kk + ko, (char*)Al + chunk * 16);
            const size_t gs = (size_t)(n0 + r) * HID + kk + ko;
            async16(Whi + gs, (char*)Bsh + chunk * 16);
            async16(Wlo + gs, (char*)Bsl + chunk * 16);
            async16(Whi + (size_t)NMASK * HID + gs, (char*)Bth + chunk * 16);
            async16(Wlo + (size_t)NMASK * HID + gs, (char*)Btl + chunk * 16);
        }
        __syncthreads();

        bf16x8 a_h[4], a_l[4];
#pragma unroll
        for (int mt = 0; mt < 4; ++mt) {
            const int r = wr * 64 + mt * 16 + nl;
            a_h[mt] = *(const bf16x8*)&Ah[r * 32 + q * 8];
            a_l[mt] = *(const bf16x8*)&Al[r * 32 + q * 8];
        }
#pragma unroll
        for (int nt = 0; nt < 4; ++nt) {
            const int c = wc * 64 + nt * 16 + nl;
            bf16x8 bs_h = *(const bf16x8*)&Bsh[c * 32 + q * 8];
            bf16x8 bs_l = *(const bf16x8*)&Bsl[c * 32 + q * 8];
            bf16x8 bt_h = *(const bf16x8*)&Bth[c * 32 + q * 8];
            bf16x8 bt_l = *(const bf16x8*)&Btl[c * 32 + q * 8];
#pragma unroll
            for (int mt = 0; mt < 4; ++mt) {
                accS[mt][nt] = __builtin_amdgcn_mfma_f32_16x16x32_bf16(a_h[mt], bs_h, accS[mt][nt], 0, 0, 0);
                accS[mt][nt] = __builtin_amdgcn_mfma_f32_16x16x32_bf16(a_h[mt], bs_l, accS[mt][nt], 0, 0, 0);
                accS[mt][nt] = __builtin_amdgcn_mfma_f32_16x16x32_bf16(a_l[mt], bs_h, accS[mt][nt], 0, 0, 0);
                accT[mt][nt] = __builtin_amdgcn_mfma_f32_16x16x32_bf16(a_h[mt], bt_h, accT[mt][nt], 0, 0, 0);
                accT[mt][nt] = __builtin_amdgcn_mfma_f32_16x16x32_bf16(a_h[mt], bt_l, accT[mt][nt], 0, 0, 0);
                accT[mt][nt] = __builtin_amdgcn_mfma_f32_16x16x32_bf16(a_l[mt], bt_h, accT[mt][nt], 0, 0, 0);
            }
        }
        __syncthreads();
    }

    // ---- epilogue ----
    ushort_t* xh = xsh + (size_t)q1 * HALF;
    ushort_t* xl = xsl + (size_t)q1 * HALF;
    float ld[4][4] = {};
#pragma unroll
    for (int mt = 0; mt < 4; ++mt) {
#pragma unroll
        for (int nt = 0; nt < 4; ++nt) {
            const int n  = n0 + wc * 64 + nt * 16 + nl;
            const float bs = b3[n];
            const float bt = b3[n + NMASK];
#pragma unroll
            for (int r = 0; r < 4; ++r) {
                const int row = row0 + wr * 64 + mt * 16 + q * 4 + r;
                const float sv = accS[mt][nt][r] + bs;
                // overflow-safe 2*tanh(sv) via fast exp
                const float e2 = __expf(-2.f * fabsf(sv));
                float th = __fdividef(1.f - e2, 1.f + e2);
                th = __builtin_copysignf(th, sv);
                const float s  = 2.f * th;
                const float es = __expf(s);
                const size_t off = (size_t)row * NMASK + n;
                const float old = bf2f(xh[off]) + bf2f(xl[off]);
                const float nv  = old * es + accT[mt][nt][r] + bt;
                unsigned short hh, ll; split2(nv, hh, ll);
                xh[off] = hh; xl[off] = ll;
                ld[mt][r] += s;
            }
        }
    }
#pragma unroll
    for (int mt = 0; mt < 4; ++mt)
#pragma unroll
        for (int r = 0; r < 4; ++r) {
            float v = ld[mt][r];
            v += __shfl_xor(v, 1);
            v += __shfl_xor(v, 2);
            v += __shfl_xor(v, 4);
            v += __shfl_xor(v, 8);
            if (nl == 0)
                atomicAdd(&logdet[row0 + wr * 64 + mt * 16 + q * 4 + r], v);
        }
}

// ---------------------------------------------------------------------------
extern "C" void kernel_launch(void* const* d_in, const int* in_sizes, int n_in,
                              void* d_out, int out_size, void* d_ws, size_t ws_size,
                              hipStream_t stream)
{
    const float* z  = (const float*)d_in[0];
    const float* W1 = (const float*)d_in[1];
    const float* b1 = (const float*)d_in[2];
    const float* W2 = (const float*)d_in[3];
    const float* b2 = (const float*)d_in[4];
    const float* W3 = (const float*)d_in[5];
    const float* b3 = (const float*)d_in[6];

    float* xout   = (float*)d_out;
    float* logdet = xout + (size_t)BATCH * NTOT;

    // workspace layout (u16 elements, then fp32 partials) -- ~250 MB total
    ushort_t* ws = (ushort_t*)d_ws;
    size_t o = 0;
    ushort_t* W1h = ws + o; o += (size_t)NLAYERS * HID * NMASK;
    ushort_t* W1l = ws + o; o += (size_t)NLAYERS * HID * NMASK;
    ushort_t* W2h = ws + o; o += (size_t)NLAYERS * HID * HID;
    ushort_t* W2l = ws + o; o += (size_t)NLAYERS * HID * HID;
    ushort_t* W3h = ws + o; o += (size_t)NLAYERS * NTOT * HID;
    ushort_t* W3l = ws + o; o += (size_t)NLAYERS * NTOT * HID;
    ushort_t* h1h = ws + o; o += (size_t)BATCH * HID;
    ushort_t* h1l = ws + o; o += (size_t)BATCH * HID;
    ushort_t* h2h = ws + o; o += (size_t)BATCH * HID;
    ushort_t* h2l = ws + o; o += (size_t)BATCH * HID;
    ushort_t* xsh = ws + o; o += 2 * HALF;
    ushort_t* xsl = ws + o; o += 2 * HALF;
    float*    P   = (float*)(ws + o);   // [4][BATCH][HID] fp32 split-K partials

    hipMemsetAsync(logdet, 0, sizeof(float) * BATCH, stream);

    // weights: transpose to n-major + hi/lo split
    split_transpose_kernel<<<dim3(NMASK / 32, HID / 32, NLAYERS), 256, 0, stream>>>(
        W1, W1h, W1l, NMASK, HID);
    split_transpose_kernel<<<dim3(HID / 32, HID / 32, NLAYERS), 256, 0, stream>>>(
        W2, W2h, W2l, HID, HID);
    split_transpose_kernel<<<dim3(HID / 32, NTOT / 32, NLAYERS), 256, 0, stream>>>(
        W3, W3h, W3l, HID, NTOT);

    // z -> dense masked-ordered hi/lo splits for both halves
    prep_split<<<dim3((unsigned)(HALF / 4 / 256)), 256, 0, stream>>>(z, xsh, xsl);

    const unsigned cgrid = (unsigned)((size_t)BATCH * HID / 4 / 256);
    for (int i = 0; i < NLAYERS; ++i) {
        const int p  = i & 1;      // masked half
        const int q1 = 1 - p;      // updated half
        // gemm1 (split-K=4): P[ks] = xm @ W1  (M=8192,N=256,K=2048)
        gemm_splitk<<<dim3(BATCH / 128, HID / 128, 4), 256, 0, stream>>>(
            xsh + (size_t)p * HALF, xsl + (size_t)p * HALF, NMASK,
            W1h + (size_t)i * HID * NMASK, W1l + (size_t)i * HID * NMASK, NMASK,
            16, P);
        combine_leaky<<<cgrid, 256, 0, stream>>>(P, 4, b1 + (size_t)i * HID, h1h, h1l);
        // gemm2 (split-K=4): P[ks] = h1 @ W2  (K=256)
        gemm_splitk<<<dim3(BATCH / 128, HID / 128, 4), 256, 0, stream>>>(
            h1h, h1l, HID,
            W2h + (size_t)i * HID * HID, W2l + (size_t)i * HID * HID, HID,
            2, P);
        combine_leaky<<<cgrid, 256, 0, stream>>>(P, 4, b2 + (size_t)i * HID, h2h, h2l);
        // gemm3 + coupling update (writes next layer's masked splits in place)
        gemm3_update<<<dim3(BATCH / 128, NMASK / 128), 256, 0, stream>>>(
            h2h, h2l,
            W3h + (size_t)i * NTOT * HID, W3l + (size_t)i * NTOT * HID,
            b3 + (size_t)i * NTOT,
            xsh, xsl, logdet, q1);
    }

    finalize_x<<<dim3((unsigned)(HALF / 4 / 256)), 256, 0, stream>>>(xsh, xsl, xout);
}